// Round 3
// baseline (157.056 us; speedup 1.0000x reference)
//
#include <hip/hip_runtime.h>
#include <hip/hip_bf16.h>

// ---------------------------------------------------------------------------
// NaiveFourierKANLayer as GEMM:  y = [cos|sin features][4096 x 32768] * W + b
// R12: kernel is LDS-read-BW-bound (512 KB/CU/ii of B-fragment ds_read_b128
//      = 41 us floor at 85 B/cyc; both R10/R11 sat on it). Re-tile waves
//      32r x 256c -> 64r x 128c (4 row-groups x 2 col-groups): each bF read
//      now feeds rf=2 MFMAs -> B LDS traffic halves (256 KB/CU/ii, ~20.5 us
//      floor). acc 2x4xf32x16=128 + aF 64 + bF 16 regs: still 2 waves/SIMD.
//      MFMA core 32x32x16 (layouts HW-verified in R11), SPLITK=16, grid 256,
//      LDS 144KB, dbuf B via global_load_lds. Image/prep/reduce unchanged.
// ---------------------------------------------------------------------------

typedef __attribute__((ext_vector_type(8))) short short8;
typedef __attribute__((ext_vector_type(16))) float f32x16;

#define SPLITK 16
#define ICHUNK (256 / SPLITK)   // 16 i's per block

#define INV2PI 0.15915494309189535f

// ---- bf16 pack helpers ----
__device__ __forceinline__ unsigned short f2bf(float f) {
    unsigned u = __builtin_bit_cast(unsigned, f);
    u += 0x7fffu + ((u >> 16) & 1u);
    return (unsigned short)(u >> 16);
}
#if __has_builtin(__builtin_amdgcn_cvt_pk_bf16_f32)
typedef __attribute__((ext_vector_type(2))) __bf16 bf16x2_t;
__device__ __forceinline__ unsigned pkbf16(float a, float b) {
    bf16x2_t v = __builtin_amdgcn_cvt_pk_bf16_f32(a, b);
    return __builtin_bit_cast(unsigned, v);
}
#else
__device__ __forceinline__ unsigned pkbf16(float a, float b) {
    unsigned ua = __builtin_bit_cast(unsigned, a) + 0x8000u;
    unsigned ub = __builtin_bit_cast(unsigned, b) + 0x8000u;
    return __builtin_amdgcn_perm(ub, ua, 0x07060302u);  // [b.hi16 | a.hi16]
}
#endif

__device__ __forceinline__ void dbl2(float c, float s, float& co, float& so) {
    float t = c + c;
    co = __builtin_fmaf(t, c, -1.f);
    so = t * s;
}
__device__ __forceinline__ void rot2(float c, float s, float cr, float sr,
                                     float& co, float& so) {
    float t = s * sr;
    co = __builtin_fmaf(c, cr, -t);
    float u = s * cr;
    so = __builtin_fmaf(c, sr, u);
}

// 8 consecutive harmonics: seeds f_b, f_{b+1} with m1=2cos(x) -> freqs b+1..b+8
__device__ __forceinline__ short8 chain8(float m1, float fm1, float f0) {
    unsigned r[4];
    float vp = fm1, v = f0;
    #pragma unroll
    for (int h = 0; h < 4; ++h) {
        float v1 = __builtin_fmaf(m1, v, -vp);
        r[h] = pkbf16(v, v1);
        float v2 = __builtin_fmaf(m1, v1, -v);
        vp = v1; v = v2;
    }
    uint4 u; u.x = r[0]; u.y = r[1]; u.z = r[2]; u.w = r[3];
    return __builtin_bit_cast(short8, u);
}

// async 16B global->LDS
__device__ __forceinline__ void async_load16(const void* g, void* l) {
    __builtin_amdgcn_global_load_lds(
        (const __attribute__((address_space(1))) unsigned int*)g,
        (__attribute__((address_space(3))) unsigned int*)l,
        16, 0, 0);
}

// ---------------------------------------------------------------------------
// prep: one block per i. Coalesced 256B-run reads, bf16 pack through LDS,
// write the 64KB/i coeff image contiguously.
// Image layout (per i, 4096 uint4), 32x32x16 order:
//   gi -> sog=gi>>6, l=gi&63; ks=sog>>3, cb=sog&7;
//   col o = cb*32+(l&31); kb = ks*16+(l>>5)*8; type t=kb>>6; g0=kb&63;
//   entry = fc[t][o][i][g0..g0+7] packed bf16 (freqs g0+1..g0+8).
// ---------------------------------------------------------------------------
__global__ __launch_bounds__(512) void prep_kernel(
    const float* __restrict__ fc, unsigned short* __restrict__ ws2)
{
    __shared__ unsigned pk[512][36];   // row = t*256+o, col = g/2; pad 32->36
    const int i = blockIdx.x;          // 0..255
    const int t = threadIdx.x;         // 0..511
    const int rr  = t >> 4;            // run-in-pass 0..31
    const int l16 = t & 15;

    #pragma unroll
    for (int p = 0; p < 16; ++p) {
        int r = p * 32 + rr;           // (type*256+o)
        const float4* src =
            (const float4*)(fc + ((size_t)r * 256 + i) * 64) + l16;
        float4 v = *src;               // g = l16*4 .. +3
        pk[r][l16 * 2]     = pkbf16(v.x, v.y);
        pk[r][l16 * 2 + 1] = pkbf16(v.z, v.w);
    }
    __syncthreads();

    #pragma unroll
    for (int gg = 0; gg < 8; ++gg) {
        int gi = gg * 512 + t;
        int sog = gi >> 6, ll = gi & 63;
        int ks = sog >> 3, cb = sog & 7;
        int o  = cb * 32 + (ll & 31);
        int kb = ks * 16 + (ll >> 5) * 8;
        int tt = kb >> 6, g0 = kb & 63;
        int r = tt * 256 + o;
        int c = g0 >> 1;               // multiple of 4 -> 16B-aligned read
        uint4 v;
        v.x = pk[r][c]; v.y = pk[r][c + 1];
        v.z = pk[r][c + 2]; v.w = pk[r][c + 3];
        ((uint4*)ws2)[(size_t)i * 4096 + gi] = v;
    }
}

// out = bias (for atomic-fallback paths)
__global__ __launch_bounds__(256) void bias_init(
    const float* __restrict__ bias, float* __restrict__ out)
{
    int idx4 = blockIdx.x * 256 + threadIdx.x;   // 0..262143
    ((float4*)out)[idx4] = ((const float4*)bias)[idx4 & 63];
}

// out = bias + sum_z bf16partial[z]
__global__ __launch_bounds__(256) void reduce_kernel(
    const unsigned short* __restrict__ pws, const float* __restrict__ bias,
    float* __restrict__ out)
{
    int idx4 = blockIdx.x * 256 + threadIdx.x;   // 0..262143 float4s
    float4 r = ((const float4*)bias)[idx4 & 63];
    #pragma unroll
    for (int z = 0; z < SPLITK; ++z) {
        ushort4 v = ((const ushort4*)pws)[(size_t)z * 262144 + idx4];
        r.x += __builtin_bit_cast(float, (unsigned)v.x << 16);
        r.y += __builtin_bit_cast(float, (unsigned)v.y << 16);
        r.z += __builtin_bit_cast(float, (unsigned)v.z << 16);
        r.w += __builtin_bit_cast(float, (unsigned)v.w << 16);
    }
    ((float4*)out)[idx4] = r;
}

template <bool USE_WS, bool PARTIAL>
__global__ __launch_bounds__(512, 2) void fkan_gemm(
    const float* __restrict__ x, const float* __restrict__ fc,
    const unsigned short* __restrict__ bws, float* __restrict__ out,
    unsigned short* __restrict__ pws)
{
    __shared__ uint4 Bimg[2][4096];        // 128 KB: full-N coeff image, dbuf
    __shared__ float xs[ICHUNK][256];      // 16 KB: x[i][row] transposed

    const int t  = threadIdx.x;            // 0..511
    const int l  = t & 63;
    const int w  = t >> 6;                 // wave 0..7
    const int rg = w >> 1;                 // row-group 0..3 (64 rows each)
    const int cg = w & 1;                  // col-group 0..1 (128 cols each)
    const int m32 = l & 31;                // MFMA row within 32
    const int h  = l >> 5;                 // k-half: k = 8h + e

    // z in low 4 bits -> blocks sharing a B i-window land on one XCD (z%8)
    const int bid = blockIdx.x;
    const int z   = bid & 15;
    const int bx  = bid >> 4;              // 0..15
    const int rowBase = bx * 256;
    const int iBase   = z * ICHUNK;

    f32x16 acc[2][4];
    #pragma unroll
    for (int a = 0; a < 2; ++a)
        #pragma unroll
        for (int b = 0; b < 4; ++b) acc[a][b] = (f32x16)0.0f;

    auto stageB = [&](int p, int i) {
        if (USE_WS) {
            const uint4* base = (const uint4*)bws + (size_t)i * 4096;
            #pragma unroll
            for (int cc = 0; cc < 8; ++cc) {
                int c = cc * 8 + w;                 // wave-uniform chunk id
                async_load16(base + (size_t)c * 64 + l, (void*)(&Bimg[p][c * 64]));
            }
        } else {
            #pragma unroll
            for (int gg = 0; gg < 8; ++gg) {
                int gi  = gg * 512 + t;
                int sog = gi >> 6, ll = gi & 63;
                int ks = sog >> 3, cb = sog & 7;
                int o  = cb * 32 + (ll & 31);
                int kb = ks * 16 + (ll >> 5) * 8;
                int tt = kb >> 6, g0 = kb & 63;
                const float4* p4 = (const float4*)(fc +
                    ((((size_t)tt * 256 + o) * 256 + i) * 64 + g0));
                float4 a = p4[0], b = p4[1];
                uint4 v;
                v.x = pkbf16(a.x, a.y); v.y = pkbf16(a.z, a.w);
                v.z = pkbf16(b.x, b.y); v.w = pkbf16(b.z, b.w);
                Bimg[p][gi] = v;
            }
        }
    };

    // ---- preamble: stage B(iter0) + x tile, one barrier ----
    stageB(0, iBase);
    {
        const int row = t >> 1;
        const int hf  = t & 1;
        const float4* px =
            (const float4*)(x + (size_t)(rowBase + row) * 256 + iBase) + hf * 2;
        float4 v0 = px[0], v1 = px[1];
        int c0 = hf * 8;
        xs[c0 + 0][row] = v0.x; xs[c0 + 1][row] = v0.y;
        xs[c0 + 2][row] = v0.z; xs[c0 + 3][row] = v0.w;
        xs[c0 + 4][row] = v1.x; xs[c0 + 5][row] = v1.y;
        xs[c0 + 6][row] = v1.z; xs[c0 + 7][row] = v1.w;
    }
    __syncthreads();

    #pragma unroll 1
    for (int ii = 0; ii < ICHUNK; ++ii) {
        const int p = ii & 1;

        // 1. async-stage next B into the other buffer (in flight during 2-3)
        if (ii + 1 < ICHUNK) stageB(p ^ 1, iBase + ii + 1);

        // 2. synthesize A fragments: rows rg*64 + rf*32 + m32, octets 16k+8h
        short8 aF[2][8];   // [rf][ks]: 0..3 cos, 4..7 sin
        #pragma unroll
        for (int rf = 0; rf < 2; ++rf) {
            float xv = xs[ii][rg * 64 + rf * 32 + m32];
            float rev = xv * INV2PI;
            float s1 = __builtin_amdgcn_sinf(rev);
            float c1 = __builtin_amdgcn_cosf(rev);
            const float m1 = c1 + c1;
            float c2, s2, c4, s4, c8, s8, c16, s16;
            dbl2(c1, s1, c2, s2);
            dbl2(c2, s2, c4, s4);
            dbl2(c4, s4, c8, s8);
            dbl2(c8, s8, c16, s16);
            float cB = h ? c8 : 1.f;      // base angle 8h
            float sB = h ? s8 : 0.f;
            #pragma unroll
            for (int k = 0; k < 4; ++k) {
                float cB1, sB1;
                rot2(cB, sB, c1, s1, cB1, sB1);        // base+1
                aF[rf][k]     = chain8(m1, cB, cB1);   // cos, freq base+1..+8
                aF[rf][4 + k] = chain8(m1, sB, sB1);   // sin, freq base+1..+8
                if (k < 3) {
                    float cN, sN;
                    rot2(cB, sB, c16, s16, cN, sN);    // next base (+16)
                    cB = cN; sB = sN;
                }
            }
        }

        // 3. MFMA: per ks, read 4 B-fragments (this wave's 128 cols),
        //    each reused by rf=0,1 -> 8 MFMAs per ks
        #pragma unroll
        for (int ks = 0; ks < 8; ++ks) {
            short8 bF[4];
            #pragma unroll
            for (int cf = 0; cf < 4; ++cf)
                bF[cf] = __builtin_bit_cast(short8,
                    Bimg[p][(ks * 8 + cg * 4 + cf) * 64 + l]);
            #pragma unroll
            for (int rf = 0; rf < 2; ++rf)
                #pragma unroll
                for (int cf = 0; cf < 4; ++cf)
                    acc[rf][cf] = __builtin_amdgcn_mfma_f32_32x32x16_bf16(
                        aF[rf][ks], bF[cf], acc[rf][cf], 0, 0, 0);
        }

        // 4. one barrier: vmcnt drain covered by steps 2-3
        __syncthreads();
    }

    // epilogue: C/D layout col=l&31, row=(e&3)+8*(e>>2)+4*(l>>5)
    const int r0 = rowBase + rg * 64 + h * 4;
    const int c0 = cg * 128 + m32;
    if (PARTIAL) {
        unsigned short* dst = pws + (size_t)z * (4096u * 256u);
        #pragma unroll
        for (int rf = 0; rf < 2; ++rf)
            #pragma unroll
            for (int cf = 0; cf < 4; ++cf)
                #pragma unroll
                for (int e = 0; e < 16; ++e) {
                    int rl = (e & 3) + 8 * (e >> 2);
                    dst[(size_t)(r0 + rf * 32 + rl) * 256 + (c0 + cf * 32)] =
                        f2bf(acc[rf][cf][e]);
                }
    } else {
        #pragma unroll
        for (int rf = 0; rf < 2; ++rf)
            #pragma unroll
            for (int cf = 0; cf < 4; ++cf)
                #pragma unroll
                for (int e = 0; e < 16; ++e) {
                    int rl = (e & 3) + 8 * (e >> 2);
                    atomicAdd(out + (size_t)(r0 + rf * 32 + rl) * 256 + (c0 + cf * 32),
                              acc[rf][cf][e]);
                }
    }
}

extern "C" void kernel_launch(void* const* d_in, const int* in_sizes, int n_in,
                              void* d_out, int out_size, void* d_ws, size_t ws_size,
                              hipStream_t stream) {
    const float* x    = (const float*)d_in[0];
    const float* fc   = (const float*)d_in[1];
    const float* bias = (const float*)d_in[2];
    float* out = (float*)d_out;
    unsigned short* bws = (unsigned short*)d_ws;

    const size_t wsCoeff = (size_t)256 * 4096 * 16;                     // 16.78 MB
    const size_t wsFull  = wsCoeff + (size_t)SPLITK * 4096 * 256 * 2;   // +33.55 MB bf16 partials
    unsigned short* pws = (unsigned short*)((char*)d_ws + wsCoeff);

    if (ws_size >= wsFull) {
        hipLaunchKernelGGL(prep_kernel, dim3(256), dim3(512), 0, stream, fc, bws);
        hipLaunchKernelGGL((fkan_gemm<true, true>), dim3(256), dim3(512), 0, stream,
                           x, fc, bws, out, pws);
        hipLaunchKernelGGL(reduce_kernel, dim3(1024), dim3(256), 0, stream,
                           pws, bias, out);
    } else if (ws_size >= wsCoeff) {
        hipLaunchKernelGGL(bias_init, dim3(1024), dim3(256), 0, stream, bias, out);
        hipLaunchKernelGGL(prep_kernel, dim3(256), dim3(512), 0, stream, fc, bws);
        hipLaunchKernelGGL((fkan_gemm<true, false>), dim3(256), dim3(512), 0, stream,
                           x, fc, bws, out, pws);
    } else {
        hipLaunchKernelGGL(bias_init, dim3(1024), dim3(256), 0, stream, bias, out);
        hipLaunchKernelGGL((fkan_gemm<false, false>), dim3(256), dim3(512), 0, stream,
                           x, fc, bws, out, pws);
    }
}

// Round 5
// 150.490 us; speedup vs baseline: 1.0436x; 1.0436x over previous
//
#include <hip/hip_runtime.h>
#include <hip/hip_bf16.h>

// ---------------------------------------------------------------------------
// NaiveFourierKANLayer as GEMM:  y = [cos|sin features][4096 x 32768] * W + b
// R14: R13 (counted-vmcnt half-tile pipeline) hardened:
//      - empty "memory"-clobber asm after every s_barrier: plain-C++ ds_reads
//        can't hoist above the barrier (cross-wave staging race, m152 class).
//      - loadXs BEFORE stage halves: compiler's x-load wait no longer drains
//        the 12 in-flight stage loads in the prologue.
//      Structure: 32 half-steps (32KB half-images, 4 rotating LDS slots),
//      stage 3 halves ahead, s_waitcnt vmcnt(8) + raw s_barrier (8 loads stay
//      in flight across barriers), s_setprio around MFMA clusters.
//      vmcnt ledger: loads for half j+3 issued at step j; at end of step j
//      outstanding={j+1..j+3}=12 -> vmcnt(8) retires exactly half j+1.
//      Tail: vmcnt(4) @ j=29, vmcnt(0) @ j=30. Tile: 32r x 256c wave,
//      32x32x16 MFMA (HW-verified), 8 waves, SPLITK=16, grid 256, LDS 144KB.
// ---------------------------------------------------------------------------

typedef __attribute__((ext_vector_type(8))) short short8;
typedef __attribute__((ext_vector_type(16))) float f32x16;

#define SPLITK 16
#define ICHUNK (256 / SPLITK)   // 16 i's per block

#define INV2PI 0.15915494309189535f

// ---- bf16 pack helpers ----
__device__ __forceinline__ unsigned short f2bf(float f) {
    unsigned u = __builtin_bit_cast(unsigned, f);
    u += 0x7fffu + ((u >> 16) & 1u);
    return (unsigned short)(u >> 16);
}
#if __has_builtin(__builtin_amdgcn_cvt_pk_bf16_f32)
typedef __attribute__((ext_vector_type(2))) __bf16 bf16x2_t;
__device__ __forceinline__ unsigned pkbf16(float a, float b) {
    bf16x2_t v = __builtin_amdgcn_cvt_pk_bf16_f32(a, b);
    return __builtin_bit_cast(unsigned, v);
}
#else
__device__ __forceinline__ unsigned pkbf16(float a, float b) {
    unsigned ua = __builtin_bit_cast(unsigned, a) + 0x8000u;
    unsigned ub = __builtin_bit_cast(unsigned, b) + 0x8000u;
    return __builtin_amdgcn_perm(ub, ua, 0x07060302u);  // [b.hi16 | a.hi16]
}
#endif

__device__ __forceinline__ void dbl2(float c, float s, float& co, float& so) {
    float t = c + c;
    co = __builtin_fmaf(t, c, -1.f);
    so = t * s;
}
__device__ __forceinline__ void rot2(float c, float s, float cr, float sr,
                                     float& co, float& so) {
    float t = s * sr;
    co = __builtin_fmaf(c, cr, -t);
    float u = s * cr;
    so = __builtin_fmaf(c, sr, u);
}

// 8 consecutive harmonics: seeds f_b, f_{b+1} with m1=2cos(x) -> freqs b+1..b+8
__device__ __forceinline__ short8 chain8(float m1, float fm1, float f0) {
    unsigned r[4];
    float vp = fm1, v = f0;
    #pragma unroll
    for (int h = 0; h < 4; ++h) {
        float v1 = __builtin_fmaf(m1, v, -vp);
        r[h] = pkbf16(v, v1);
        float v2 = __builtin_fmaf(m1, v1, -v);
        vp = v1; v = v2;
    }
    uint4 u; u.x = r[0]; u.y = r[1]; u.z = r[2]; u.w = r[3];
    return __builtin_bit_cast(short8, u);
}

// async 16B global->LDS
__device__ __forceinline__ void async_load16(const void* g, void* l) {
    __builtin_amdgcn_global_load_lds(
        (const __attribute__((address_space(1))) unsigned int*)g,
        (__attribute__((address_space(3))) unsigned int*)l,
        16, 0, 0);
}

// ---------------------------------------------------------------------------
// prep: one block per i. Coalesced 256B-run reads, bf16 pack through LDS,
// write the 64KB/i coeff image contiguously.
// Image layout (per i, 4096 uint4), 32x32x16 order:
//   gi -> sog=gi>>6, l=gi&63; ks=sog>>3, cb=sog&7;
//   col o = cb*32+(l&31); kb = ks*16+(l>>5)*8; type t=kb>>6; g0=kb&63;
//   entry = fc[t][o][i][g0..g0+7] packed bf16 (freqs g0+1..g0+8).
// Halves: gi<2048 = ks0..3 (cos), gi>=2048 = ks4..7 (sin).
// ---------------------------------------------------------------------------
__global__ __launch_bounds__(512) void prep_kernel(
    const float* __restrict__ fc, unsigned short* __restrict__ ws2)
{
    __shared__ unsigned pk[512][36];   // row = t*256+o, col = g/2; pad 32->36
    const int i = blockIdx.x;          // 0..255
    const int t = threadIdx.x;         // 0..511
    const int rr  = t >> 4;            // run-in-pass 0..31
    const int l16 = t & 15;

    #pragma unroll
    for (int p = 0; p < 16; ++p) {
        int r = p * 32 + rr;           // (type*256+o)
        const float4* src =
            (const float4*)(fc + ((size_t)r * 256 + i) * 64) + l16;
        float4 v = *src;               // g = l16*4 .. +3
        pk[r][l16 * 2]     = pkbf16(v.x, v.y);
        pk[r][l16 * 2 + 1] = pkbf16(v.z, v.w);
    }
    __syncthreads();

    #pragma unroll
    for (int gg = 0; gg < 8; ++gg) {
        int gi = gg * 512 + t;
        int sog = gi >> 6, ll = gi & 63;
        int ks = sog >> 3, cb = sog & 7;
        int o  = cb * 32 + (ll & 31);
        int kb = ks * 16 + (ll >> 5) * 8;
        int tt = kb >> 6, g0 = kb & 63;
        int r = tt * 256 + o;
        int c = g0 >> 1;               // multiple of 4 -> 16B-aligned read
        uint4 v;
        v.x = pk[r][c]; v.y = pk[r][c + 1];
        v.z = pk[r][c + 2]; v.w = pk[r][c + 3];
        ((uint4*)ws2)[(size_t)i * 4096 + gi] = v;
    }
}

// out = bias (for atomic-fallback paths)
__global__ __launch_bounds__(256) void bias_init(
    const float* __restrict__ bias, float* __restrict__ out)
{
    int idx4 = blockIdx.x * 256 + threadIdx.x;   // 0..262143
    ((float4*)out)[idx4] = ((const float4*)bias)[idx4 & 63];
}

// out = bias + sum_z bf16partial[z]
__global__ __launch_bounds__(256) void reduce_kernel(
    const unsigned short* __restrict__ pws, const float* __restrict__ bias,
    float* __restrict__ out)
{
    int idx4 = blockIdx.x * 256 + threadIdx.x;   // 0..262143 float4s
    float4 r = ((const float4*)bias)[idx4 & 63];
    #pragma unroll
    for (int z = 0; z < SPLITK; ++z) {
        ushort4 v = ((const ushort4*)pws)[(size_t)z * 262144 + idx4];
        r.x += __builtin_bit_cast(float, (unsigned)v.x << 16);
        r.y += __builtin_bit_cast(float, (unsigned)v.y << 16);
        r.z += __builtin_bit_cast(float, (unsigned)v.z << 16);
        r.w += __builtin_bit_cast(float, (unsigned)v.w << 16);
    }
    ((float4*)out)[idx4] = r;
}

template <bool USE_WS, bool PARTIAL>
__global__ __launch_bounds__(512, 2) void fkan_gemm(
    const float* __restrict__ x, const float* __restrict__ fc,
    const unsigned short* __restrict__ bws, float* __restrict__ out,
    unsigned short* __restrict__ pws)
{
    __shared__ uint4 Bflat[8192];          // 128 KB: 4 slots x 32KB half-image
    __shared__ float xs[ICHUNK][256];      // 16 KB: x[i][row] transposed

    const int t  = threadIdx.x;            // 0..511
    const int l  = t & 63;
    const int w  = t >> 6;                 // wave 0..7 (32 rows each)
    const int m32 = l & 31;                // MFMA row within 32
    const int h  = l >> 5;                 // k-half: k = 8h + e

    // z in low 4 bits -> blocks sharing a B i-window land on one XCD (z%8)
    const int bid = blockIdx.x;
    const int z   = bid & 15;
    const int bx  = bid >> 4;              // 0..15
    const int rowBase = bx * 256;
    const int iBase   = z * ICHUNK;

    f32x16 acc[8];
    #pragma unroll
    for (int a = 0; a < 8; ++a) acc[a] = (f32x16)0.0f;

    short8 aF[8];   // [ks]: 0..3 cos, 4..7 sin

    // stage one 32KB half-image (half-step j: image iBase+(j>>1), half j&1)
    auto stageHalf = [&](int slot, int j) {
        const uint4* base = (const uint4*)bws +
            (size_t)(iBase + (j >> 1)) * 4096 + (j & 1) * 2048;
        uint4* dst = Bflat + slot * 2048;
        #pragma unroll
        for (int cc = 0; cc < 4; ++cc) {
            int c = cc * 8 + w;                 // wave-uniform chunk 0..31
            async_load16(base + (size_t)c * 64 + l, (void*)(dst + c * 64));
        }
    };

    // synthesize this lane's 8 A fragments for column i (verified R11 math)
    auto synth = [&](int ii) {
        float xv = xs[ii][w * 32 + m32];
        float rev = xv * INV2PI;
        float s1 = __builtin_amdgcn_sinf(rev);
        float c1 = __builtin_amdgcn_cosf(rev);
        const float m1 = c1 + c1;
        float c2, s2, c4, s4, c8, s8, c16, s16;
        dbl2(c1, s1, c2, s2);
        dbl2(c2, s2, c4, s4);
        dbl2(c4, s4, c8, s8);
        dbl2(c8, s8, c16, s16);
        float cB = h ? c8 : 1.f;      // base angle 8h
        float sB = h ? s8 : 0.f;
        #pragma unroll
        for (int k = 0; k < 4; ++k) {
            float cB1, sB1;
            rot2(cB, sB, c1, s1, cB1, sB1);        // base+1
            aF[k]     = chain8(m1, cB, cB1);       // cos, freq base+1..+8
            aF[4 + k] = chain8(m1, sB, sB1);       // sin, freq base+1..+8
            if (k < 3) {
                float cN, sN;
                rot2(cB, sB, c16, s16, cN, sN);    // next base (+16)
                cB = cN; sB = sN;
            }
        }
    };

    // 4 ks-steps x 8 cols on one half-image slot; A frags by value (static)
    auto mfmaHalf = [&](int slot, short8 a0, short8 a1, short8 a2, short8 a3) {
        const uint4* Bp = Bflat + slot * 2048;
        short8 av[4] = {a0, a1, a2, a3};
        #pragma unroll
        for (int ks = 0; ks < 4; ++ks) {
            short8 bF[8];
            #pragma unroll
            for (int cf = 0; cf < 8; ++cf)
                bF[cf] = __builtin_bit_cast(short8, Bp[(ks * 8 + cf) * 64 + l]);
            #pragma unroll
            for (int cf = 0; cf < 8; ++cf)
                acc[cf] = __builtin_amdgcn_mfma_f32_32x32x16_bf16(
                    av[ks], bF[cf], acc[cf], 0, 0, 0);
        }
    };

    auto loadXs = [&]() {
        const int row = t >> 1;
        const int hf  = t & 1;
        const float4* px =
            (const float4*)(x + (size_t)(rowBase + row) * 256 + iBase) + hf * 2;
        float4 v0 = px[0], v1 = px[1];
        int c0 = hf * 8;
        xs[c0 + 0][row] = v0.x; xs[c0 + 1][row] = v0.y;
        xs[c0 + 2][row] = v0.z; xs[c0 + 3][row] = v0.w;
        xs[c0 + 4][row] = v1.x; xs[c0 + 5][row] = v1.y;
        xs[c0 + 6][row] = v1.z; xs[c0 + 7][row] = v1.w;
    };

    if constexpr (USE_WS) {
        // ---- prologue: xs first (its register-load wait happens while no
        // stage loads are outstanding), then stage halves 0,1,2 ----
        loadXs();
        stageHalf(0, 0);
        stageHalf(1, 1);
        stageHalf(2, 2);
        // retire half 0 (halves 1,2 stay in flight); xs ds_writes drained;
        // then cross-wave publish
        asm volatile("s_waitcnt vmcnt(8) lgkmcnt(0)" ::: "memory");
        __builtin_amdgcn_s_barrier();
        asm volatile("" ::: "memory");   // no ds_read hoists above barrier

        #pragma unroll 1
        for (int jj = 0; jj < 16; ++jj) {
            const int j0 = jj * 2;

            // ---- even half-step j0: cos half (ks 0..3) ----
            if (jj <= 14) stageHalf((j0 + 3) & 3, j0 + 3);
            synth(jj);
            __builtin_amdgcn_s_setprio(1);
            mfmaHalf(j0 & 3, aF[0], aF[1], aF[2], aF[3]);
            __builtin_amdgcn_s_setprio(0);
            if (jj < 15) asm volatile("s_waitcnt vmcnt(8)" ::: "memory");
            else         asm volatile("s_waitcnt vmcnt(0)" ::: "memory");
            __builtin_amdgcn_s_barrier();
            asm volatile("" ::: "memory");

            // ---- odd half-step j0+1: sin half (ks 4..7) ----
            if (jj <= 13) stageHalf((j0 + 4) & 3, j0 + 4);
            __builtin_amdgcn_s_setprio(1);
            mfmaHalf((j0 + 1) & 3, aF[4], aF[5], aF[6], aF[7]);
            __builtin_amdgcn_s_setprio(0);
            if (jj < 14) {
                asm volatile("s_waitcnt vmcnt(8)" ::: "memory");
                __builtin_amdgcn_s_barrier();
                asm volatile("" ::: "memory");
            } else if (jj == 14) {
                asm volatile("s_waitcnt vmcnt(4)" ::: "memory");
                __builtin_amdgcn_s_barrier();
                asm volatile("" ::: "memory");
            }
            // jj==15: last half-step, fall through to epilogue
        }
    } else {
        // ---- fallback (no workspace): 2-phase __syncthreads loop ----
        auto stageBfc = [&](int p, int i) {
            #pragma unroll
            for (int gg = 0; gg < 8; ++gg) {
                int gi  = gg * 512 + t;
                int sog = gi >> 6, ll = gi & 63;
                int ks = sog >> 3, cb = sog & 7;
                int o  = cb * 32 + (ll & 31);
                int kb = ks * 16 + (ll >> 5) * 8;
                int tt = kb >> 6, g0 = kb & 63;
                const float4* p4 = (const float4*)(fc +
                    ((((size_t)tt * 256 + o) * 256 + i) * 64 + g0));
                float4 a = p4[0], b = p4[1];
                uint4 v;
                v.x = pkbf16(a.x, a.y); v.y = pkbf16(a.z, a.w);
                v.z = pkbf16(b.x, b.y); v.w = pkbf16(b.z, b.w);
                Bflat[p * 4096 + gi] = v;
            }
        };
        stageBfc(0, iBase);
        loadXs();
        __syncthreads();
        #pragma unroll 1
        for (int ii = 0; ii < ICHUNK; ++ii) {
            const int p = ii & 1;
            if (ii + 1 < ICHUNK) stageBfc(p ^ 1, iBase + ii + 1);
            synth(ii);
            mfmaHalf(p * 2,     aF[0], aF[1], aF[2], aF[3]);
            mfmaHalf(p * 2 + 1, aF[4], aF[5], aF[6], aF[7]);
            __syncthreads();
        }
    }

    // epilogue: C/D layout col=l&31, row=(e&3)+8*(e>>2)+4*(l>>5)
    const int r0 = rowBase + w * 32 + h * 4;
    if (PARTIAL) {
        unsigned short* dst = pws + (size_t)z * (4096u * 256u);
        #pragma unroll
        for (int cf = 0; cf < 8; ++cf)
            #pragma unroll
            for (int e = 0; e < 16; ++e) {
                int rl = (e & 3) + 8 * (e >> 2);
                dst[(size_t)(r0 + rl) * 256 + (cf * 32 + m32)] =
                    f2bf(acc[cf][e]);
            }
    } else {
        #pragma unroll
        for (int cf = 0; cf < 8; ++cf)
            #pragma unroll
            for (int e = 0; e < 16; ++e) {
                int rl = (e & 3) + 8 * (e >> 2);
                atomicAdd(out + (size_t)(r0 + rl) * 256 + (cf * 32 + m32),
                          acc[cf][e]);
            }
    }
}

extern "C" void kernel_launch(void* const* d_in, const int* in_sizes, int n_in,
                              void* d_out, int out_size, void* d_ws, size_t ws_size,
                              hipStream_t stream) {
    const float* x    = (const float*)d_in[0];
    const float* fc   = (const float*)d_in[1];
    const float* bias = (const float*)d_in[2];
    float* out = (float*)d_out;
    unsigned short* bws = (unsigned short*)d_ws;

    const size_t wsCoeff = (size_t)256 * 4096 * 16;                     // 16.78 MB
    const size_t wsFull  = wsCoeff + (size_t)SPLITK * 4096 * 256 * 2;   // +33.55 MB bf16 partials
    unsigned short* pws = (unsigned short*)((char*)d_ws + wsCoeff);

    if (ws_size >= wsFull) {
        hipLaunchKernelGGL(prep_kernel, dim3(256), dim3(512), 0, stream, fc, bws);
        hipLaunchKernelGGL((fkan_gemm<true, true>), dim3(256), dim3(512), 0, stream,
                           x, fc, bws, out, pws);
        hipLaunchKernelGGL(reduce_kernel, dim3(1024), dim3(256), 0, stream,
                           pws, bias, out);
    } else if (ws_size >= wsCoeff) {
        hipLaunchKernelGGL(bias_init, dim3(1024), dim3(256), 0, stream, bias, out);
        hipLaunchKernelGGL(prep_kernel, dim3(256), dim3(512), 0, stream, fc, bws);
        hipLaunchKernelGGL((fkan_gemm<true, false>), dim3(256), dim3(512), 0, stream,
                           x, fc, bws, out, pws);
    } else {
        hipLaunchKernelGGL(bias_init, dim3(1024), dim3(256), 0, stream, bias, out);
        hipLaunchKernelGGL((fkan_gemm<false, false>), dim3(256), dim3(512), 0, stream,
                           x, fc, bws, out, pws);
    }
}